// Round 4
// baseline (429.598 us; speedup 1.0000x reference)
//
#include <hip/hip_runtime.h>
#include <cstdint>
#include <cstddef>

// Problem constants
#define NROWS   16384
#define L1DIM   3072
#define NEXP    8
#define NO1     16        // L2+1 outputs of layer 1
#define NFEAT   30        // 2*15 features into layer 2
#define NL3     32
#define RFEAT   32        // ROUTER_FEATS

// Main-kernel tiling
#define RPB     32        // rows per block
#define KC      192       // K chunk
#define KC4     48        // KC/4 float4s per row
#define NCHUNK  16        // 3072/192
#define PITCH   196       // LDS pitch in floats (196%32==4 -> rows rotate banks; conflict-free)
#define NKS     8         // k-slices (half-wave each)
#define KSL     24        // K floats per slice
#define SENT    0x7FFFFFFF
#define RBLK    256       // router/scatter grid (16384/64)
#define MAXSLOTS (NROWS + NEXP*RPB)   // 16640
#define MBLK    (MAXSLOTS/RPB)        // 520

// Device-static scratch (fully rewritten before every read each call; d_ws unused).
__device__ int g_eid[NROWS];
__device__ int g_bc[RBLK*NEXP];
__device__ int g_base[RBLK*NEXP];   // per-block exclusive base per expert
__device__ int g_off[NEXP+1];
__device__ int g_bucket[MAXSLOTS];

// ---------------- K1: router + per-block histogram (64 thr/block) ----------------
__global__ __launch_bounds__(64) void k_router(const float* __restrict__ x,
                                               const float* __restrict__ rw,
                                               const float* __restrict__ rb){
  int tid = threadIdx.x;
  int row = blockIdx.x*64 + tid;
  const float* xr = x + (size_t)row * L1DIM;
  float rin[2*RFEAT];
  #pragma unroll
  for (int i=0;i<8;i++){
    float4 v = *(const float4*)(xr + i*4);
    rin[i*4+0]=v.x; rin[i*4+1]=v.y; rin[i*4+2]=v.z; rin[i*4+3]=v.w;
  }
  #pragma unroll
  for (int i=0;i<8;i++){
    float4 v = *(const float4*)(xr + (L1DIM/2) + i*4);
    rin[32+i*4+0]=v.x; rin[32+i*4+1]=v.y; rin[32+i*4+2]=v.z; rin[32+i*4+3]=v.w;
  }
  float best = -3.0e38f; int be = 0;
  #pragma unroll
  for (int e=0;e<NEXP;e++){
    float s = rb[e];
    #pragma unroll
    for (int i=0;i<64;i++) s += rin[i]*rw[e*64+i];
    if (s > best){ best = s; be = e; }   // strict > keeps first max (jnp.argmax)
  }
  g_eid[row] = be;
  __shared__ int cnt[NEXP];
  if (tid < NEXP) cnt[tid] = 0;
  __syncthreads();
  atomicAdd(&cnt[be], 1);
  __syncthreads();
  if (tid < NEXP) g_bc[blockIdx.x*NEXP + tid] = cnt[tid];
}

// ---------------- K2: counts -> offsets + per-block bases (LDS scan) + pad fill ----
__global__ __launch_bounds__(256) void k_offsets(){
  __shared__ int sbc[RBLK*NEXP];     // 8 KB: all per-block counts
  __shared__ int gpart[32*NEXP];     // group partials
  __shared__ int gpre[32*NEXP];      // group exclusive prefixes
  __shared__ int scnt[NEXP];
  __shared__ int soff[NEXP+1];
  int tid = threadIdx.x;
  #pragma unroll
  for (int p=0;p<8;p++) sbc[tid + p*256] = g_bc[tid + p*256];
  __syncthreads();
  int e = tid & 7, g = tid >> 3;     // g in [0,32): group of 8 consecutive blocks
  {
    int s = 0;
    #pragma unroll
    for (int b=0;b<8;b++) s += sbc[(g*8+b)*NEXP + e];
    gpart[g*NEXP + e] = s;
  }
  __syncthreads();
  if (tid < NEXP){                   // serial scan over 32 groups (LDS, fast)
    int run = 0;
    for (int gg=0;gg<32;gg++){
      gpre[gg*NEXP + tid] = run;
      run += gpart[gg*NEXP + tid];
    }
    scnt[tid] = run;
  }
  __syncthreads();
  if (tid == 0){
    int o = 0;
    for (int ee=0; ee<NEXP; ee++){
      soff[ee] = o;
      o += ((scnt[ee] + RPB - 1) / RPB) * RPB;
    }
    soff[NEXP] = o;
    for (int i=0;i<=NEXP;i++) g_off[i] = soff[i];
  }
  __syncthreads();
  {                                  // per-block exclusive bases
    int run = soff[e] + gpre[g*NEXP + e];
    #pragma unroll
    for (int b=0;b<8;b++){
      g_base[(g*8+b)*NEXP + e] = run;
      run += sbc[(g*8+b)*NEXP + e];
    }
  }
  for (int ee=0; ee<NEXP; ee++){     // sentinel-fill padding
    int s    = soff[ee] + scnt[ee];
    int epad = soff[ee+1];
    for (int i = s + tid; i < epad; i += 256) g_bucket[i] = SENT;
  }
}

// ---------------- K3: deterministic atomic-free scatter (one wave/block) ----------
__global__ __launch_bounds__(64) void k_scatter(){
  int lane = threadIdx.x;
  int row = blockIdx.x*64 + lane;
  int e = g_eid[row];
  unsigned long long peers = 0;
  #pragma unroll
  for (int j=0;j<NEXP;j++){
    unsigned long long m = __ballot(e == j);
    if (e == j) peers = m;
  }
  int rank = __popcll(peers & ((1ull << lane) - 1ull));
  g_bucket[g_base[blockIdx.x*NEXP + e] + rank] = row;
}

// ---------------- K4: 32-row GEMM (3072->16), dbuf LDS + reg prefetch, fused MLP ----
__global__ __launch_bounds__(256) void k_main(const float* __restrict__ x,
    const float* __restrict__ l1w, const float* __restrict__ l1b,
    const float* __restrict__ l2w, const float* __restrict__ l2b,
    const float* __restrict__ ow,  const float* __restrict__ ob,
    float* __restrict__ out){
  __shared__ __align__(16) float sX[2][RPB][PITCH];   // 50176 B
  __shared__ __align__(16) float sW[2][NO1][PITCH];   // 25088 B
  __shared__ int sRows[RPB];
  __shared__ int sE;

  int tid = threadIdx.x;
  int slot0 = blockIdx.x * RPB;
  if (tid == 0){
    int e = -1;
    if (slot0 < g_off[NEXP]){
      #pragma unroll
      for (int j=0;j<NEXP;j++) if (slot0 >= g_off[j] && slot0 < g_off[j+1]) e = j;
    }
    sE = e;
  }
  __syncthreads();
  int e = sE;
  if (e < 0) return;
  if (tid < RPB) sRows[tid] = g_bucket[slot0 + tid];
  __syncthreads();

  const char* xb = (const char*)x;
  const char* wb = (const char*)(l1w + (size_t)e * (NO1 * L1DIM));

  // per-thread staging geometry (fixed across chunks); byte offsets
  unsigned xgo[6], xlo[6], wgo[3], wlo[3];
  #pragma unroll
  for (int p=0;p<6;p++){
    int i = tid + p*256, r = i / KC4, k4 = i % KC4;
    int gr = sRows[r]; if (gr == SENT) gr = 0;
    xgo[p] = (unsigned)gr * (L1DIM*4) + (unsigned)k4 * 16;
    xlo[p] = ((unsigned)r * PITCH + (unsigned)k4 * 4) * 4;
  }
  #pragma unroll
  for (int p=0;p<3;p++){
    int i = tid + p*256, o = i / KC4, k4 = i % KC4;
    wgo[p] = (unsigned)o * (L1DIM*4) + (unsigned)k4 * 16;
    wlo[p] = ((unsigned)o * PITCH + (unsigned)k4 * 4) * 4;
  }

  int ks = tid >> 5;       // k-slice 0..7 (half-wave each)
  int l5 = tid & 31;
  int og = l5 & 3;
  int rg = l5 >> 2;

  float acc[4][4];
  #pragma unroll
  for (int i=0;i<4;i++)
    #pragma unroll
    for (int j=0;j<4;j++) acc[i][j] = 0.f;

  float4 rx[6], rw4[3];
  char* sXb = (char*)&sX[0][0][0];
  char* sWb = (char*)&sW[0][0][0];
  const unsigned XBUF = RPB*PITCH*4, WBUF = NO1*PITCH*4;

  // ---- prologue: chunk 0 ----
  #pragma unroll
  for (int p=0;p<6;p++) rx[p]  = *(const float4*)(xb + xgo[p]);
  #pragma unroll
  for (int p=0;p<3;p++) rw4[p] = *(const float4*)(wb + wgo[p]);
  #pragma unroll
  for (int p=0;p<6;p++) *(float4*)(sXb + xlo[p]) = rx[p];
  #pragma unroll
  for (int p=0;p<3;p++) *(float4*)(sWb + wlo[p]) = rw4[p];
  __syncthreads();

  for (int c=0; c<NCHUNK-1; c++){
    unsigned kb = (unsigned)(c+1) * (KC*4);
    // T14: issue next chunk's loads into registers (vmcnt waited at the LDS write)
    #pragma unroll
    for (int p=0;p<6;p++) rx[p]  = *(const float4*)(xb + xgo[p] + kb);
    #pragma unroll
    for (int p=0;p<3;p++) rw4[p] = *(const float4*)(wb + wgo[p] + kb);
    // compute current chunk
    {
      int buf = c & 1;
      const float (*cX)[PITCH] = sX[buf];
      const float (*cW)[PITCH] = sW[buf];
      int k0 = ks * KSL;
      #pragma unroll
      for (int q=0;q<KSL/4;q++){
        int k = k0 + q*4;
        float4 xv[4], wv[4];
        #pragma unroll
        for (int i=0;i<4;i++) xv[i] = *(const float4*)(&cX[rg + i*8][k]);
        #pragma unroll
        for (int j=0;j<4;j++) wv[j] = *(const float4*)(&cW[og + j*4][k]);
        #pragma unroll
        for (int ri=0;ri<4;ri++)
          #pragma unroll
          for (int oi=0;oi<4;oi++){
            acc[ri][oi] += xv[ri].x * wv[oi].x;
            acc[ri][oi] += xv[ri].y * wv[oi].y;
            acc[ri][oi] += xv[ri].z * wv[oi].z;
            acc[ri][oi] += xv[ri].w * wv[oi].w;
          }
      }
    }
    // write prefetched chunk into the other buffer
    {
      unsigned bo = (unsigned)((c+1)&1);
      char* dX = sXb + bo*XBUF;
      char* dW = sWb + bo*WBUF;
      #pragma unroll
      for (int p=0;p<6;p++) *(float4*)(dX + xlo[p]) = rx[p];
      #pragma unroll
      for (int p=0;p<3;p++) *(float4*)(dW + wlo[p]) = rw4[p];
    }
    __syncthreads();
  }
  // final chunk compute (buf = (NCHUNK-1)&1 = 1)
  {
    const float (*cX)[PITCH] = sX[1];
    const float (*cW)[PITCH] = sW[1];
    int k0 = ks * KSL;
    #pragma unroll
    for (int q=0;q<KSL/4;q++){
      int k = k0 + q*4;
      float4 xv[4], wv[4];
      #pragma unroll
      for (int i=0;i<4;i++) xv[i] = *(const float4*)(&cX[rg + i*8][k]);
      #pragma unroll
      for (int j=0;j<4;j++) wv[j] = *(const float4*)(&cW[og + j*4][k]);
      #pragma unroll
      for (int ri=0;ri<4;ri++)
        #pragma unroll
        for (int oi=0;oi<4;oi++){
          acc[ri][oi] += xv[ri].x * wv[oi].x;
          acc[ri][oi] += xv[ri].y * wv[oi].y;
          acc[ri][oi] += xv[ri].z * wv[oi].z;
          acc[ri][oi] += xv[ri].w * wv[oi].w;
        }
    }
  }

  // cross-k-slice reduction through LDS buffer 0 ([8][32][17] floats = 17408 B)
  __syncthreads();
  float* red = &sX[0][0][0];
  #pragma unroll
  for (int ri=0;ri<4;ri++)
    #pragma unroll
    for (int oi=0;oi<4;oi++)
      red[(ks*RPB + (rg + ri*8))*17 + (og + oi*4)] = acc[ri][oi];
  __syncthreads();

  // fused epilogue: 4 threads per row, 8 layer-2 outs each (tid < 128 active)
  if (tid < RPB*4){
    int row = tid >> 2;
    int g   = tid & 3;
    float l1c[NO1];
    #pragma unroll
    for (int j=0;j<NO1;j++){
      float s = l1b[e*NO1 + j];
      #pragma unroll
      for (int sl=0;sl<NKS;sl++) s += red[(sl*RPB + row)*17 + j];
      l1c[j] = s;
    }
    float feat[NFEAT];
    #pragma unroll
    for (int j=0;j<15;j++){
      float v = l1c[j];
      feat[j]    = fminf(v*v*(255.0f/256.0f), 1.0f);
      feat[15+j] = fminf(fmaxf(v, 0.0f), 1.0f);
    }
    float l1xout = l1c[15];
    const float* w2 = l2w + e*NL3*NFEAT;
    const float* wo = ow  + e*NL3;
    float acc3 = 0.f;
    #pragma unroll
    for (int oo=0;oo<8;oo++){
      int o = g*8 + oo;
      float s = l2b[e*NL3 + o];
      #pragma unroll
      for (int i=0;i<NFEAT;i++) s += feat[i]*w2[o*NFEAT + i];
      s = fminf(fmaxf(s, 0.0f), 1.0f);
      acc3 += s * wo[o];
    }
    acc3 += __shfl_xor(acc3, 1);
    acc3 += __shfl_xor(acc3, 2);
    if (g == 0){
      int grow = sRows[row];
      if (grow != SENT) out[grow] = acc3 + ob[e] + l1xout;
    }
  }
}

extern "C" void kernel_launch(void* const* d_in, const int* in_sizes, int n_in,
                              void* d_out, int out_size, void* d_ws, size_t ws_size,
                              hipStream_t stream){
  (void)in_sizes; (void)n_in; (void)d_ws; (void)ws_size; (void)out_size;
  const float* x   = (const float*)d_in[0];
  const float* rw  = (const float*)d_in[1];
  const float* rb  = (const float*)d_in[2];
  const float* l1w = (const float*)d_in[3];
  const float* l1b = (const float*)d_in[4];
  const float* l2w = (const float*)d_in[5];
  const float* l2b = (const float*)d_in[6];
  const float* ow  = (const float*)d_in[7];
  const float* ob  = (const float*)d_in[8];
  float* out = (float*)d_out;

  hipLaunchKernelGGL(k_router,  dim3(RBLK), dim3(64),  0, stream, x, rw, rb);
  hipLaunchKernelGGL(k_offsets, dim3(1),    dim3(256), 0, stream);
  hipLaunchKernelGGL(k_scatter, dim3(RBLK), dim3(64),  0, stream);
  hipLaunchKernelGGL(k_main,    dim3(MBLK), dim3(256), 0, stream,
                     x, l1w, l1b, l2w, l2b, ow, ob, out);
}

// Round 5
// 416.318 us; speedup vs baseline: 1.0319x; 1.0319x over previous
//
#include <hip/hip_runtime.h>
#include <cstdint>
#include <cstddef>

// Problem constants
#define NROWS   16384
#define L1DIM   3072
#define NEXP    8
#define NO1     16        // L2+1 outputs of layer 1
#define NFEAT   30        // 2*15 features into layer 2
#define NL3     32
#define RFEAT   32        // ROUTER_FEATS

// Main-kernel tiling: 16 rows/block, W-in-LDS only, x direct from global.
#define RPB     16        // rows per block (4 per wave)
#define KCH     512       // K chunk (floats) staged in LDS for W
#define NCH     6         // 3072/512
#define SENT    0x7FFFFFFF
#define RBLK    256       // router/scatter grid (16384/64)
#define MAXSLOTS (NROWS + NEXP*RPB)   // 16512
#define MBLK    (MAXSLOTS/RPB)        // 1032

// Device-static scratch (fully rewritten before every read each call; d_ws unused).
__device__ int g_eid[NROWS];
__device__ int g_bc[RBLK*NEXP];
__device__ int g_base[RBLK*NEXP];   // per-block exclusive base per expert
__device__ int g_off[NEXP+1];
__device__ int g_bucket[MAXSLOTS];

// ---------------- K1: router + per-block histogram (64 thr/block) ----------------
__global__ __launch_bounds__(64) void k_router(const float* __restrict__ x,
                                               const float* __restrict__ rw,
                                               const float* __restrict__ rb){
  int tid = threadIdx.x;
  int row = blockIdx.x*64 + tid;
  const float* xr = x + (size_t)row * L1DIM;
  float rin[2*RFEAT];
  #pragma unroll
  for (int i=0;i<8;i++){
    float4 v = *(const float4*)(xr + i*4);
    rin[i*4+0]=v.x; rin[i*4+1]=v.y; rin[i*4+2]=v.z; rin[i*4+3]=v.w;
  }
  #pragma unroll
  for (int i=0;i<8;i++){
    float4 v = *(const float4*)(xr + (L1DIM/2) + i*4);
    rin[32+i*4+0]=v.x; rin[32+i*4+1]=v.y; rin[32+i*4+2]=v.z; rin[32+i*4+3]=v.w;
  }
  float best = -3.0e38f; int be = 0;
  #pragma unroll
  for (int e=0;e<NEXP;e++){
    float s = rb[e];
    #pragma unroll
    for (int i=0;i<64;i++) s += rin[i]*rw[e*64+i];
    if (s > best){ best = s; be = e; }   // strict > keeps first max (jnp.argmax)
  }
  g_eid[row] = be;
  __shared__ int cnt[NEXP];
  if (tid < NEXP) cnt[tid] = 0;
  __syncthreads();
  atomicAdd(&cnt[be], 1);
  __syncthreads();
  if (tid < NEXP) g_bc[blockIdx.x*NEXP + tid] = cnt[tid];
}

// ---------------- K2: counts -> offsets + per-block bases (LDS scan) + pad fill ----
__global__ __launch_bounds__(256) void k_offsets(){
  __shared__ int sbc[RBLK*NEXP];     // 8 KB: all per-block counts
  __shared__ int gpart[32*NEXP];     // group partials
  __shared__ int gpre[32*NEXP];      // group exclusive prefixes
  __shared__ int scnt[NEXP];
  __shared__ int soff[NEXP+1];
  int tid = threadIdx.x;
  #pragma unroll
  for (int p=0;p<8;p++) sbc[tid + p*256] = g_bc[tid + p*256];
  __syncthreads();
  int e = tid & 7, g = tid >> 3;     // g in [0,32): group of 8 consecutive blocks
  {
    int s = 0;
    #pragma unroll
    for (int b=0;b<8;b++) s += sbc[(g*8+b)*NEXP + e];
    gpart[g*NEXP + e] = s;
  }
  __syncthreads();
  if (tid < NEXP){                   // serial scan over 32 groups (LDS, fast)
    int run = 0;
    for (int gg=0;gg<32;gg++){
      gpre[gg*NEXP + tid] = run;
      run += gpart[gg*NEXP + tid];
    }
    scnt[tid] = run;
  }
  __syncthreads();
  if (tid == 0){
    int o = 0;
    for (int ee=0; ee<NEXP; ee++){
      soff[ee] = o;
      o += ((scnt[ee] + RPB - 1) / RPB) * RPB;
    }
    soff[NEXP] = o;
    for (int i=0;i<=NEXP;i++) g_off[i] = soff[i];
  }
  __syncthreads();
  {                                  // per-block exclusive bases
    int run = soff[e] + gpre[g*NEXP + e];
    #pragma unroll
    for (int b=0;b<8;b++){
      g_base[(g*8+b)*NEXP + e] = run;
      run += sbc[(g*8+b)*NEXP + e];
    }
  }
  for (int ee=0; ee<NEXP; ee++){     // sentinel-fill padding
    int s    = soff[ee] + scnt[ee];
    int epad = soff[ee+1];
    for (int i = s + tid; i < epad; i += 256) g_bucket[i] = SENT;
  }
}

// ---------------- K3: deterministic atomic-free scatter (one wave/block) ----------
__global__ __launch_bounds__(64) void k_scatter(){
  int lane = threadIdx.x;
  int row = blockIdx.x*64 + lane;
  int e = g_eid[row];
  unsigned long long peers = 0;
  #pragma unroll
  for (int j=0;j<NEXP;j++){
    unsigned long long m = __ballot(e == j);
    if (e == j) peers = m;
  }
  int rank = __popcll(peers & ((1ull << lane) - 1ull));
  g_bucket[g_base[blockIdx.x*NEXP + e] + rank] = row;
}

// ---------------- K4: 16-row GEMM, K-across-lanes, x direct global, W in LDS ----
__global__ __launch_bounds__(256,3) void k_main(const float* __restrict__ x,
    const float* __restrict__ l1w, const float* __restrict__ l1b,
    const float* __restrict__ l2w, const float* __restrict__ l2b,
    const float* __restrict__ ow,  const float* __restrict__ ob,
    float* __restrict__ out){
  __shared__ __align__(16) float sW[NO1][KCH];   // 32768 B, single buffer
  __shared__ int sRows[RPB];
  __shared__ int sE;

  int tid = threadIdx.x;
  int slot0 = blockIdx.x * RPB;
  if (tid == 0){
    int e = -1;
    if (slot0 < g_off[NEXP]){
      #pragma unroll
      for (int j=0;j<NEXP;j++) if (slot0 >= g_off[j] && slot0 < g_off[j+1]) e = j;
    }
    sE = e;
  }
  __syncthreads();
  int e = sE;
  if (e < 0) return;
  if (tid < RPB) sRows[tid] = g_bucket[slot0 + tid];
  __syncthreads();

  int lane = tid & 63;
  int wid  = tid >> 6;                 // wave 0..3; wave owns rows wid*4..wid*4+3
  const char* xb = (const char*)x;
  const char* wb = (const char*)(l1w + (size_t)e * (NO1 * L1DIM));
  char* sWb = (char*)&sW[0][0];

  unsigned xoff[4];
  #pragma unroll
  for (int r=0;r<4;r++){
    int gr = sRows[wid*4 + r];
    int use = (gr == SENT) ? 0 : gr;
    xoff[r] = (unsigned)use * (L1DIM*4) + (unsigned)lane * 16;
  }

  float acc[4][16];
  #pragma unroll
  for (int r=0;r<4;r++)
    #pragma unroll
    for (int o=0;o<16;o++) acc[r][o] = 0.f;

  for (int c=0; c<NCH; c++){
    unsigned cb = (unsigned)c * (KCH*4);
    __syncthreads();
    // stage W chunk: 2048 float4s, 8 per thread (coalesced 2 KB runs per o-row)
    #pragma unroll
    for (int p=0;p<8;p++){
      int idx = tid + p*256;
      int o  = idx >> 7;               // 0..15
      int k4 = idx & 127;
      float4 v = *(const float4*)(wb + (unsigned)o*(L1DIM*4) + cb + (unsigned)k4*16);
      *(float4*)(sWb + (unsigned)idx*16) = v;
    }
    __syncthreads();
    #pragma unroll
    for (int it=0; it<2; it++){
      float4 xv[4];
      #pragma unroll
      for (int r=0;r<4;r++)
        xv[r] = *(const float4*)(xb + xoff[r] + cb + it*1024);
      #pragma unroll
      for (int o=0;o<16;o++){
        float4 wv = *(const float4*)(sWb + o*(KCH*4) + it*1024 + lane*16);
        #pragma unroll
        for (int r=0;r<4;r++){
          acc[r][o] += xv[r].x * wv.x;
          acc[r][o] += xv[r].y * wv.y;
          acc[r][o] += xv[r].z * wv.z;
          acc[r][o] += xv[r].w * wv.w;
        }
      }
    }
  }

  // 6-round butterfly allreduce over 64 lanes (every lane ends with full sums)
  #pragma unroll
  for (int m=1; m<64; m<<=1){
    #pragma unroll
    for (int r=0;r<4;r++)
      #pragma unroll
      for (int o=0;o<16;o++)
        acc[r][o] += __shfl_xor(acc[r][o], m, 64);
  }

  // epilogue: 16 lanes per row; static-index extraction (no runtime reg indexing)
  int row = lane >> 4;                 // 0..3
  int og  = lane & 15;                 // out-group: layer2 outs og*2, og*2+1
  float l1c[NO1];
  #pragma unroll
  for (int j=0;j<NO1;j++){
    float v = acc[0][j];
    if (row == 1) v = acc[1][j];
    if (row == 2) v = acc[2][j];
    if (row == 3) v = acc[3][j];
    l1c[j] = v + l1b[e*NO1 + j];
  }
  float feat[NFEAT];
  #pragma unroll
  for (int j=0;j<15;j++){
    float v = l1c[j];
    feat[j]    = fminf(v*v*(255.0f/256.0f), 1.0f);   // square >= 0 already
    feat[15+j] = fminf(fmaxf(v, 0.0f), 1.0f);
  }
  float l1xout = l1c[15];
  const float* w2 = l2w + e*NL3*NFEAT;
  const float* wo = ow  + e*NL3;
  float acc3 = 0.f;
  #pragma unroll
  for (int oo=0;oo<2;oo++){
    int o = og*2 + oo;
    float s = l2b[e*NL3 + o];
    #pragma unroll
    for (int i=0;i<NFEAT;i++) s += feat[i]*w2[o*NFEAT + i];
    s = fminf(fmaxf(s, 0.0f), 1.0f);
    acc3 += s * wo[o];
  }
  acc3 += __shfl_xor(acc3, 1);
  acc3 += __shfl_xor(acc3, 2);
  acc3 += __shfl_xor(acc3, 4);
  acc3 += __shfl_xor(acc3, 8);
  if (og == 0){
    int gr = sRows[wid*4 + row];
    if (gr != SENT) out[gr] = acc3 + ob[e] + l1xout;
  }
}

extern "C" void kernel_launch(void* const* d_in, const int* in_sizes, int n_in,
                              void* d_out, int out_size, void* d_ws, size_t ws_size,
                              hipStream_t stream){
  (void)in_sizes; (void)n_in; (void)d_ws; (void)ws_size; (void)out_size;
  const float* x   = (const float*)d_in[0];
  const float* rw  = (const float*)d_in[1];
  const float* rb  = (const float*)d_in[2];
  const float* l1w = (const float*)d_in[3];
  const float* l1b = (const float*)d_in[4];
  const float* l2w = (const float*)d_in[5];
  const float* l2b = (const float*)d_in[6];
  const float* ow  = (const float*)d_in[7];
  const float* ob  = (const float*)d_in[8];
  float* out = (float*)d_out;

  hipLaunchKernelGGL(k_router,  dim3(RBLK), dim3(64),  0, stream, x, rw, rb);
  hipLaunchKernelGGL(k_offsets, dim3(1),    dim3(256), 0, stream);
  hipLaunchKernelGGL(k_scatter, dim3(RBLK), dim3(64),  0, stream);
  hipLaunchKernelGGL(k_main,    dim3(MBLK), dim3(256), 0, stream,
                     x, l1w, l1b, l2w, l2b, ow, ob, out);
}

// Round 6
// 328.609 us; speedup vs baseline: 1.3073x; 1.2669x over previous
//
#include <hip/hip_runtime.h>
#include <cstdint>
#include <cstddef>

// Problem constants
#define NROWS   16384
#define L1DIM   3072
#define NEXP    8
#define NO1     16        // L2+1 outputs of layer 1
#define NFEAT   30        // 2*15 features into layer 2
#define NL3     32
#define RFEAT   32        // ROUTER_FEATS

// Main-kernel tiling: 16 rows/block, 128-float K chunks, 4x4 outer-product tiles.
#define RPB     16        // rows per block -> 1032 blocks ~= 4 blocks/CU
#define KC      128       // K chunk (floats)
#define NCH     24        // 3072/128
#define PITCH   132       // LDS pitch (128+4): rows rotate banks by 4 dwords
#define SENT    0x7FFFFFFF
#define RBLK    256       // router/scatter grid (16384/64)
#define MAXSLOTS (NROWS + NEXP*RPB)   // 16512
#define MBLK    (MAXSLOTS/RPB)        // 1032

// Device-static scratch (fully rewritten before every read each call; d_ws unused).
__device__ int g_eid[NROWS];
__device__ int g_bc[RBLK*NEXP];
__device__ int g_base[RBLK*NEXP];   // per-block exclusive base per expert
__device__ int g_off[NEXP+1];
__device__ int g_bucket[MAXSLOTS];

// ---------------- K1: router + per-block histogram (64 thr/block) ----------------
__global__ __launch_bounds__(64) void k_router(const float* __restrict__ x,
                                               const float* __restrict__ rw,
                                               const float* __restrict__ rb){
  int tid = threadIdx.x;
  int row = blockIdx.x*64 + tid;
  const float* xr = x + (size_t)row * L1DIM;
  float rin[2*RFEAT];
  #pragma unroll
  for (int i=0;i<8;i++){
    float4 v = *(const float4*)(xr + i*4);
    rin[i*4+0]=v.x; rin[i*4+1]=v.y; rin[i*4+2]=v.z; rin[i*4+3]=v.w;
  }
  #pragma unroll
  for (int i=0;i<8;i++){
    float4 v = *(const float4*)(xr + (L1DIM/2) + i*4);
    rin[32+i*4+0]=v.x; rin[32+i*4+1]=v.y; rin[32+i*4+2]=v.z; rin[32+i*4+3]=v.w;
  }
  float best = -3.0e38f; int be = 0;
  #pragma unroll
  for (int e=0;e<NEXP;e++){
    float s = rb[e];
    #pragma unroll
    for (int i=0;i<64;i++) s += rin[i]*rw[e*64+i];
    if (s > best){ best = s; be = e; }   // strict > keeps first max (jnp.argmax)
  }
  g_eid[row] = be;
  __shared__ int cnt[NEXP];
  if (tid < NEXP) cnt[tid] = 0;
  __syncthreads();
  atomicAdd(&cnt[be], 1);
  __syncthreads();
  if (tid < NEXP) g_bc[blockIdx.x*NEXP + tid] = cnt[tid];
}

// ---------------- K2: counts -> offsets + per-block bases (LDS scan) + pad fill ----
__global__ __launch_bounds__(256) void k_offsets(){
  __shared__ int sbc[RBLK*NEXP];     // 8 KB: all per-block counts
  __shared__ int gpart[32*NEXP];     // group partials
  __shared__ int gpre[32*NEXP];      // group exclusive prefixes
  __shared__ int scnt[NEXP];
  __shared__ int soff[NEXP+1];
  int tid = threadIdx.x;
  #pragma unroll
  for (int p=0;p<8;p++) sbc[tid + p*256] = g_bc[tid + p*256];
  __syncthreads();
  int e = tid & 7, g = tid >> 3;     // g in [0,32): group of 8 consecutive blocks
  {
    int s = 0;
    #pragma unroll
    for (int b=0;b<8;b++) s += sbc[(g*8+b)*NEXP + e];
    gpart[g*NEXP + e] = s;
  }
  __syncthreads();
  if (tid < NEXP){                   // serial scan over 32 groups (LDS, fast)
    int run = 0;
    for (int gg=0;gg<32;gg++){
      gpre[gg*NEXP + tid] = run;
      run += gpart[gg*NEXP + tid];
    }
    scnt[tid] = run;
  }
  __syncthreads();
  if (tid == 0){
    int o = 0;
    for (int ee=0; ee<NEXP; ee++){
      soff[ee] = o;
      o += ((scnt[ee] + RPB - 1) / RPB) * RPB;
    }
    soff[NEXP] = o;
    for (int i=0;i<=NEXP;i++) g_off[i] = soff[i];
  }
  __syncthreads();
  {                                  // per-block exclusive bases
    int run = soff[e] + gpre[g*NEXP + e];
    #pragma unroll
    for (int b=0;b<8;b++){
      g_base[(g*8+b)*NEXP + e] = run;
      run += sbc[(g*8+b)*NEXP + e];
    }
  }
  for (int ee=0; ee<NEXP; ee++){     // sentinel-fill padding
    int s    = soff[ee] + scnt[ee];
    int epad = soff[ee+1];
    for (int i = s + tid; i < epad; i += 256) g_bucket[i] = SENT;
  }
}

// ---------------- K3: deterministic atomic-free scatter (one wave/block) ----------
__global__ __launch_bounds__(64) void k_scatter(){
  int lane = threadIdx.x;
  int row = blockIdx.x*64 + lane;
  int e = g_eid[row];
  unsigned long long peers = 0;
  #pragma unroll
  for (int j=0;j<NEXP;j++){
    unsigned long long m = __ballot(e == j);
    if (e == j) peers = m;
  }
  int rank = __popcll(peers & ((1ull << lane) - 1ull));
  g_bucket[g_base[blockIdx.x*NEXP + e] + rank] = row;
}

// ---------------- K4: 16-row GEMM (3072->16), 4x4 tiles, 16 k-slices, fused MLP ----
__global__ __launch_bounds__(256) void k_main(const float* __restrict__ x,
    const float* __restrict__ l1w, const float* __restrict__ l1b,
    const float* __restrict__ l2w, const float* __restrict__ l2b,
    const float* __restrict__ ow,  const float* __restrict__ ob,
    float* __restrict__ out){
  __shared__ __align__(16) float sX[RPB][PITCH];     // 8448 B
  __shared__ __align__(16) float sW[NO1][PITCH];     // 8448 B
  __shared__ __align__(16) float sRed[4][RPB][17];   // 4352 B cross-wave reduce
  __shared__ int sRows[RPB];
  __shared__ int sE;

  int tid = threadIdx.x;
  int slot0 = blockIdx.x * RPB;
  if (tid == 0){
    int e = -1;
    if (slot0 < g_off[NEXP]){
      #pragma unroll
      for (int j=0;j<NEXP;j++) if (slot0 >= g_off[j] && slot0 < g_off[j+1]) e = j;
    }
    sE = e;
  }
  __syncthreads();
  int e = sE;
  if (e < 0) return;
  if (tid < RPB) sRows[tid] = g_bucket[slot0 + tid];
  __syncthreads();

  const char* xb = (const char*)x;
  const char* wb = (const char*)(l1w + (size_t)e * (NO1 * L1DIM));
  char* sXb = (char*)&sX[0][0];
  char* sWb = (char*)&sW[0][0];

  // staging geometry: 512 float4s each for X and W, 2 per thread
  unsigned xgo[2], xlo[2], wgo[2], wlo[2];
  #pragma unroll
  for (int p=0;p<2;p++){
    int i = tid + p*256, r = i >> 5, k4 = i & 31;   // 32 float4s per 128-float row
    int gr = sRows[r]; if (gr == SENT) gr = 0;
    xgo[p] = (unsigned)gr * (L1DIM*4) + (unsigned)k4 * 16;
    xlo[p] = ((unsigned)r * PITCH + (unsigned)k4 * 4) * 4;
    wgo[p] = (unsigned)r * (L1DIM*4) + (unsigned)k4 * 16;  // r doubles as o (16 rows)
    wlo[p] = xlo[p] - 0;  // same local layout
  }

  int lane = tid & 63;
  int wid  = tid >> 6;
  int ks   = tid >> 4;       // k-slice 0..15 (quarter-wave each)
  int slot = tid & 15;
  int og   = slot & 3;       // outs og, og+4, og+8, og+12
  int rg   = slot >> 2;      // rows rg, rg+4, rg+8, rg+12

  float acc[4][4];
  #pragma unroll
  for (int i=0;i<4;i++)
    #pragma unroll
    for (int j=0;j<4;j++) acc[i][j] = 0.f;

  for (int c=0; c<NCH; c++){
    unsigned cb = (unsigned)c * (KC*4);
    __syncthreads();
    #pragma unroll
    for (int p=0;p<2;p++){
      float4 xv = *(const float4*)(xb + xgo[p] + cb);
      float4 wv = *(const float4*)(wb + wgo[p] + cb);
      *(float4*)(sXb + xlo[p]) = xv;
      *(float4*)(sWb + wlo[p]) = wv;
    }
    __syncthreads();
    #pragma unroll
    for (int q=0;q<2;q++){
      int k = ks*8 + q*4;
      float4 xv[4], wv[4];
      #pragma unroll
      for (int i=0;i<4;i++) xv[i] = *(const float4*)(&sX[rg + 4*i][k]);
      #pragma unroll
      for (int j=0;j<4;j++) wv[j] = *(const float4*)(&sW[og + 4*j][k]);
      #pragma unroll
      for (int i=0;i<4;i++)
        #pragma unroll
        for (int j=0;j<4;j++){
          acc[i][j] += xv[i].x * wv[j].x;
          acc[i][j] += xv[i].y * wv[j].y;
          acc[i][j] += xv[i].z * wv[j].z;
          acc[i][j] += xv[i].w * wv[j].w;
        }
    }
  }

  // intra-wave reduction over the 4 k-slices in this wave (lane bits 4,5)
  #pragma unroll
  for (int i=0;i<4;i++)
    #pragma unroll
    for (int j=0;j<4;j++){
      acc[i][j] += __shfl_xor(acc[i][j], 16, 64);
      acc[i][j] += __shfl_xor(acc[i][j], 32, 64);
    }
  // cross-wave partials to LDS (one writer slot-set per wave)
  if (lane < 16){
    #pragma unroll
    for (int i=0;i<4;i++)
      #pragma unroll
      for (int j=0;j<4;j++)
        sRed[wid][rg + 4*i][og + 4*j] = acc[i][j];
  }
  __syncthreads();

  // fused epilogue: 4 threads per row (tid < 64)
  if (tid < RPB*4){
    int row = tid >> 2;
    int g   = tid & 3;
    float l1c[NO1];
    #pragma unroll
    for (int j=0;j<NO1;j++){
      float s = l1b[e*NO1 + j];
      #pragma unroll
      for (int w=0;w<4;w++) s += sRed[w][row][j];
      l1c[j] = s;
    }
    float feat[NFEAT];
    #pragma unroll
    for (int j=0;j<15;j++){
      float v = l1c[j];
      feat[j]    = fminf(v*v*(255.0f/256.0f), 1.0f);   // square >= 0 already
      feat[15+j] = fminf(fmaxf(v, 0.0f), 1.0f);
    }
    float l1xout = l1c[15];
    const float* w2 = l2w + e*NL3*NFEAT;
    const float* wo = ow  + e*NL3;
    float acc3 = 0.f;
    #pragma unroll
    for (int oo=0;oo<8;oo++){
      int o = g*8 + oo;
      float s = l2b[e*NL3 + o];
      #pragma unroll
      for (int i=0;i<NFEAT;i++) s += feat[i]*w2[o*NFEAT + i];
      s = fminf(fmaxf(s, 0.0f), 1.0f);
      acc3 += s * wo[o];
    }
    acc3 += __shfl_xor(acc3, 1);
    acc3 += __shfl_xor(acc3, 2);
    if (g == 0){
      int grow = sRows[row];
      if (grow != SENT) out[grow] = acc3 + ob[e] + l1xout;
    }
  }
}

extern "C" void kernel_launch(void* const* d_in, const int* in_sizes, int n_in,
                              void* d_out, int out_size, void* d_ws, size_t ws_size,
                              hipStream_t stream){
  (void)in_sizes; (void)n_in; (void)d_ws; (void)ws_size; (void)out_size;
  const float* x   = (const float*)d_in[0];
  const float* rw  = (const float*)d_in[1];
  const float* rb  = (const float*)d_in[2];
  const float* l1w = (const float*)d_in[3];
  const float* l1b = (const float*)d_in[4];
  const float* l2w = (const float*)d_in[5];
  const float* l2b = (const float*)d_in[6];
  const float* ow  = (const float*)d_in[7];
  const float* ob  = (const float*)d_in[8];
  float* out = (float*)d_out;

  hipLaunchKernelGGL(k_router,  dim3(RBLK), dim3(64),  0, stream, x, rw, rb);
  hipLaunchKernelGGL(k_offsets, dim3(1),    dim3(256), 0, stream);
  hipLaunchKernelGGL(k_scatter, dim3(RBLK), dim3(64),  0, stream);
  hipLaunchKernelGGL(k_main,    dim3(MBLK), dim3(256), 0, stream,
                     x, l1w, l1b, l2w, l2b, ow, ob, out);
}